// Round 6
// baseline (973.686 us; speedup 1.0000x reference)
//
#include <hip/hip_runtime.h>

#define DI __device__ __forceinline__

typedef __bf16 bf16x8 __attribute__((ext_vector_type(8)));
typedef float  f32x4  __attribute__((ext_vector_type(4)));
typedef float  f32x2  __attribute__((ext_vector_type(2)));

DI f32x4 splat4(float b) { f32x4 v; v[0] = b; v[1] = b; v[2] = b; v[3] = b; return v; }

// tanh-form GELU: gelu(x) = x / (1 + exp(-2u)), u = 0.79788456(x + 0.044715x^3)
DI float gelu_fast(float x) {
    float x3 = x * x * x;
    float z = -1.5957691216057308f * fmaf(0.044715f, x3, x);
    float e = __expf(z);
    return __fdividef(x, 1.0f + e);
}

// ---------------- prep: transpose weights to bf16 Bt[n][k] layouts ----------------
__global__ void prep_w(const float* __restrict__ cW1, const float* __restrict__ cW2,
                       const float* __restrict__ oW1, const float* __restrict__ oW2,
                       __bf16* __restrict__ ws) {
    int id = blockIdx.x * 256 + threadIdx.x;
    if (id < 12288) {
        int n = id >> 5, k = id & 31;
        ws[id] = (k < 12) ? (__bf16)cW1[k * 384 + n] : (__bf16)0.0f;
    } else if (id < 86016) {
        int t = id - 12288;
        int n = t / 384, k = t % 384;
        ws[id] = (__bf16)cW2[k * 192 + n];
    } else if (id < 159744) {
        int t = id - 86016;
        int n = t / 192, k = t % 192;
        ws[id] = (__bf16)oW1[k * 384 + n];
    } else if (id < 233472) {
        int t = id - 159744;
        int n = t / 384, k = t % 384;
        ws[id] = (__bf16)oW2[k * 192 + n];
    }
}

// flag projection table: 128 combos x 192, exact erf GELU, f32
__global__ void prep_ft(const float* __restrict__ W1, const float* __restrict__ b1,
                        const float* __restrict__ W2, const float* __restrict__ b2,
                        float* __restrict__ ftab) {
    __shared__ float h[384];
    int c = blockIdx.x;
    int tid = threadIdx.x;  // 0..191
    #pragma unroll
    for (int half = 0; half < 2; ++half) {
        int j = tid + half * 192;
        float v = b1[j];
        #pragma unroll
        for (int i = 0; i < 7; ++i)
            if (c & (1 << i)) v += W1[i * 384 + j];
        h[j] = 0.5f * v * (1.0f + erff(v * 0.70710678118654752f));
    }
    __syncthreads();
    float acc = b2[tid];
    for (int j = 0; j < 384; ++j)
        acc += h[j] * W2[j * 192 + tid];
    ftab[c * 192 + tid] = acc;
}

// pack 6 indices + flag-code into one uint2 per move
__global__ void prep_pack(const float* __restrict__ flags,
                          const int* __restrict__ from_sq, const int* __restrict__ to_sq,
                          const int* __restrict__ kind_id, const int* __restrict__ promo_id,
                          const int* __restrict__ meta_id, const int* __restrict__ mover,
                          const int* __restrict__ target, uint2* __restrict__ pk, int N) {
    int t = blockIdx.x * 256 + threadIdx.x;
    if (t >= N) return;
    unsigned fc = 0;
    #pragma unroll
    for (int i = 0; i < 7; ++i) fc |= (flags[t * 7 + i] > 0.5f) ? (1u << i) : 0u;
    unsigned a = (unsigned)mover[t] | ((unsigned)target[t] << 8) |
                 ((unsigned)from_sq[t] << 16) | ((unsigned)to_sq[t] << 24);
    unsigned b = (unsigned)kind_id[t] | ((unsigned)promo_id[t] << 8) |
                 ((unsigned)meta_id[t] << 16) | (fc << 24);
    uint2 v; v.x = a; v.y = b;
    pk[t] = v;
}

// ---------------- fused main kernel: 4 waves cooperate on 64 moves ----------------
// LDS: [0,24576)     region A: h1 low half (h1 [64][384]bf16 spans A+B), then x[64][192], then h2 cols 192..383
//      [24576,49152) region B: h1 high half, then h2 cols 0..191
//      [49152,51200) region P: LN partials [64 rows][4 waves][2] f32
// Register budget: target <=128 VGPR (the tier the allocator picks; LDS allows 3 blocks/CU
// = 12 waves/CU only if VGPR<=128). No phase may exceed ~110 live f32:
//   gather: acc2(48); C1: acc2(48)+af(16)+acc1(24); C2: acc2(48)+frags(28);
//   C3: acc3(48)+frags(28); C4: acc4(48)+frags(28).  acc3/acc4 NEVER co-live.
__global__ __launch_bounds__(256, 2) void me_main(
    const float* __restrict__ cons, const uint2* __restrict__ pk,
    const float* __restrict__ gctx, const float* __restrict__ piece,
    const float* __restrict__ sqe, const float* __restrict__ kinde,
    const float* __restrict__ promoe, const float* __restrict__ metae,
    const float* __restrict__ cons_b1, const float* __restrict__ cons_b2,
    const float* __restrict__ ln_g, const float* __restrict__ ln_b,
    const float* __restrict__ out_b1, const float* __restrict__ out_b2,
    const __bf16* __restrict__ cW1t, const __bf16* __restrict__ cW2t,
    const __bf16* __restrict__ oW1t, const __bf16* __restrict__ oW2t,
    const float* __restrict__ ftab, float* __restrict__ out) {
    __shared__ __align__(16) char sm[51200];
    float* P = (float*)(sm + 49152);
    const int tid = threadIdx.x;
    const int w = tid >> 6;        // wave 0..3
    const int lane = tid & 63;
    const int lg = lane >> 4;      // 0..3
    const int lr = lane & 15;      // 0..15
    const int mb = blockIdx.x * 64;
    const int wc = w * 48;         // this wave's tok/out col base

    // ---- gathers -> acc2 (tok) in MFMA C-layout: row rt*16+lg*4+r, col wc+ct*16+lr
    f32x4 acc2[4][3];
    {
        float basev[3];
        #pragma unroll
        for (int ct = 0; ct < 3; ++ct) {
            int n = wc + ct * 16 + lr;
            basev[ct] = gctx[n] + cons_b2[n];
        }
        #pragma unroll
        for (int rt = 0; rt < 4; ++rt) {
            #pragma unroll
            for (int r = 0; r < 4; ++r) {
                int M = mb + rt * 16 + lg * 4 + r;
                uint2 k2 = pk[M];
                const float* p0 = piece + (k2.x & 0xffu) * 192;
                const float* p1 = piece + ((k2.x >> 8) & 0xffu) * 192;
                const float* p2 = sqe + ((k2.x >> 16) & 0xffu) * 192;
                const float* p3 = sqe + (k2.x >> 24) * 192;
                const float* p4 = kinde + (k2.y & 0xffu) * 192;
                const float* p5 = promoe + ((k2.y >> 8) & 0xffu) * 192;
                const float* p6 = metae + ((k2.y >> 16) & 0xffu) * 192;
                const float* p7 = ftab + (k2.y >> 24) * 192;
                #pragma unroll
                for (int ct = 0; ct < 3; ++ct) {
                    int n = wc + ct * 16 + lr;
                    acc2[rt][ct][r] = basev[ct] + p0[n] + p1[n] + p2[n] + p3[n]
                                    + p4[n] + p5[n] + p6[n] + p7[n];
                }
            }
        }
    }

    // ---- C1: h1 = gelu(cons @ W1 + b1); wave w produces h1 cols [w*96, w*96+96)
    {
        bf16x8 af[4];
        #pragma unroll
        for (int rt = 0; rt < 4; ++rt) {
            int M = mb + rt * 16 + lr;
            #pragma unroll
            for (int i = 0; i < 8; ++i) {
                int k = lg * 8 + i;
                float v = (k < 12) ? cons[M * 12 + k] : 0.0f;
                af[rt][i] = (__bf16)v;
            }
        }
        #pragma unroll
        for (int hh = 0; hh < 2; ++hh) {
            #pragma unroll
            for (int rp = 0; rp < 2; ++rp) {   // rt-pairs: acc1 is 24 regs, not 48
                f32x4 acc1[2][3];
                #pragma unroll
                for (int ct = 0; ct < 3; ++ct) {
                    int n0 = w * 96 + hh * 48 + ct * 16;
                    float b1v = cons_b1[n0 + lr];
                    bf16x8 bf = *(const bf16x8*)(cW1t + (n0 + lr) * 32 + lg * 8);
                    #pragma unroll
                    for (int rr = 0; rr < 2; ++rr)
                        acc1[rr][ct] = __builtin_amdgcn_mfma_f32_16x16x32_bf16(af[rp * 2 + rr], bf, splat4(b1v), 0, 0, 0);
                }
                #pragma unroll
                for (int rr = 0; rr < 2; ++rr)
                    #pragma unroll
                    for (int ct = 0; ct < 3; ++ct)
                        #pragma unroll
                        for (int r = 0; r < 4; ++r) {
                            int row = (rp * 2 + rr) * 16 + lg * 4 + r;
                            int col = w * 96 + hh * 48 + ct * 16 + lr;
                            *(__bf16*)(sm + ((row * 768 + 2 * col) ^ ((row & 7) << 4))) =
                                (__bf16)gelu_fast(acc1[rr][ct][r]);
                        }
            }
        }
    }
    __syncthreads();  // h1 complete

    // ---- C2: tok += h1 @ cons_W2 (K=384)
    #pragma unroll
    for (int ks = 0; ks < 12; ++ks) {
        bf16x8 a[4], b[3];
        #pragma unroll
        for (int rt = 0; rt < 4; ++rt) {
            int row = rt * 16 + lr;
            a[rt] = *(const bf16x8*)(sm + ((row * 768 + ks * 64 + lg * 16) ^ ((row & 7) << 4)));
        }
        #pragma unroll
        for (int ct = 0; ct < 3; ++ct)
            b[ct] = *(const bf16x8*)(cW2t + (wc + ct * 16 + lr) * 384 + ks * 32 + lg * 8);
        #pragma unroll
        for (int rt = 0; rt < 4; ++rt)
            #pragma unroll
            for (int ct = 0; ct < 3; ++ct)
                acc2[rt][ct] = __builtin_amdgcn_mfma_f32_16x16x32_bf16(a[rt], b[ct], acc2[rt][ct], 0, 0, 0);
    }

    // ---- LN partials: per-row (s, s2) over this wave's 48 cols, butterfly over lr
    #pragma unroll
    for (int rt = 0; rt < 4; ++rt) {
        #pragma unroll
        for (int r = 0; r < 4; ++r) {
            float v0 = acc2[rt][0][r], v1 = acc2[rt][1][r], v2 = acc2[rt][2][r];
            float s = v0 + v1 + v2;
            float s2 = v0 * v0 + v1 * v1 + v2 * v2;
            s += __shfl_xor(s, 1); s2 += __shfl_xor(s2, 1);
            s += __shfl_xor(s, 2); s2 += __shfl_xor(s2, 2);
            s += __shfl_xor(s, 4); s2 += __shfl_xor(s2, 4);
            s += __shfl_xor(s, 8); s2 += __shfl_xor(s2, 8);
            if (lr == 0) {
                int row = rt * 16 + lg * 4 + r;
                f32x2 pv; pv[0] = s; pv[1] = s2;
                *(f32x2*)(P + row * 8 + w * 2) = pv;
            }
        }
    }
    __syncthreads();  // partials visible; all h1 reads done (regions reusable)

    // ---- LN finalize -> x bf16 into region A [64][192]
    {
        float lngv[3], lnbv[3];
        #pragma unroll
        for (int ct = 0; ct < 3; ++ct) {
            int n = wc + ct * 16 + lr;
            lngv[ct] = ln_g[n];
            lnbv[ct] = ln_b[n];
        }
        #pragma unroll
        for (int rt = 0; rt < 4; ++rt) {
            #pragma unroll
            for (int r = 0; r < 4; ++r) {
                int row = rt * 16 + lg * 4 + r;
                f32x4 pa = *(const f32x4*)(P + row * 8);
                f32x4 pb = *(const f32x4*)(P + row * 8 + 4);
                float s = pa[0] + pa[2] + pb[0] + pb[2];
                float s2 = pa[1] + pa[3] + pb[1] + pb[3];
                float mu = s * (1.0f / 192.0f);
                float var = s2 * (1.0f / 192.0f) - mu * mu;
                float inv = rsqrtf(var + 1e-5f);
                #pragma unroll
                for (int ct = 0; ct < 3; ++ct) {
                    int n = wc + ct * 16 + lr;
                    float xv = (acc2[rt][ct][r] - mu) * inv * lngv[ct] + lnbv[ct];
                    *(__bf16*)(sm + ((row * 384 + 2 * n) ^ ((row & 7) << 4))) = (__bf16)xv;
                }
            }
        }
    }
    __syncthreads();  // x ready

    // ---- C3 half0: h2 cols [0,192) = gelu(x @ oW1 half0) -> region B
    {
        f32x4 acc3[4][3];
        #pragma unroll
        for (int ct = 0; ct < 3; ++ct) {
            float b1v = out_b1[wc + ct * 16 + lr];
            #pragma unroll
            for (int rt = 0; rt < 4; ++rt) acc3[rt][ct] = splat4(b1v);
        }
        #pragma unroll
        for (int ks = 0; ks < 6; ++ks) {
            bf16x8 a[4], b[3];
            #pragma unroll
            for (int rt = 0; rt < 4; ++rt) {
                int row = rt * 16 + lr;
                a[rt] = *(const bf16x8*)(sm + ((row * 384 + ks * 64 + lg * 16) ^ ((row & 7) << 4)));
            }
            #pragma unroll
            for (int ct = 0; ct < 3; ++ct) {
                int tt = w * 3 + ct;
                b[ct] = *(const bf16x8*)(oW1t + (tt * 16 + lr) * 192 + ks * 32 + lg * 8);
            }
            #pragma unroll
            for (int rt = 0; rt < 4; ++rt)
                #pragma unroll
                for (int ct = 0; ct < 3; ++ct)
                    acc3[rt][ct] = __builtin_amdgcn_mfma_f32_16x16x32_bf16(a[rt], b[ct], acc3[rt][ct], 0, 0, 0);
        }
        #pragma unroll
        for (int rt = 0; rt < 4; ++rt)
            #pragma unroll
            for (int ct = 0; ct < 3; ++ct)
                #pragma unroll
                for (int r = 0; r < 4; ++r) {
                    int row = rt * 16 + lg * 4 + r;
                    int c = wc + ct * 16 + lr;
                    *(__bf16*)(sm + 24576 + ((row * 384 + 2 * c) ^ ((row & 7) << 4))) =
                        (__bf16)gelu_fast(acc3[rt][ct][r]);
                }
    }

    // ---- C3 half1: compute in regs while x still valid, then overwrite region A
    {
        f32x4 acc3[4][3];
        #pragma unroll
        for (int ct = 0; ct < 3; ++ct) {
            float b1v = out_b1[192 + wc + ct * 16 + lr];
            #pragma unroll
            for (int rt = 0; rt < 4; ++rt) acc3[rt][ct] = splat4(b1v);
        }
        #pragma unroll
        for (int ks = 0; ks < 6; ++ks) {
            bf16x8 a[4], b[3];
            #pragma unroll
            for (int rt = 0; rt < 4; ++rt) {
                int row = rt * 16 + lr;
                a[rt] = *(const bf16x8*)(sm + ((row * 384 + ks * 64 + lg * 16) ^ ((row & 7) << 4)));
            }
            #pragma unroll
            for (int ct = 0; ct < 3; ++ct) {
                int tt = 12 + w * 3 + ct;
                b[ct] = *(const bf16x8*)(oW1t + (tt * 16 + lr) * 192 + ks * 32 + lg * 8);
            }
            #pragma unroll
            for (int rt = 0; rt < 4; ++rt)
                #pragma unroll
                for (int ct = 0; ct < 3; ++ct)
                    acc3[rt][ct] = __builtin_amdgcn_mfma_f32_16x16x32_bf16(a[rt], b[ct], acc3[rt][ct], 0, 0, 0);
        }
        __syncthreads();  // ALL waves done reading x before region A is overwritten
        #pragma unroll
        for (int rt = 0; rt < 4; ++rt)
            #pragma unroll
            for (int ct = 0; ct < 3; ++ct)
                #pragma unroll
                for (int r = 0; r < 4; ++r) {
                    int row = rt * 16 + lg * 4 + r;
                    int c = wc + ct * 16 + lr;
                    *(__bf16*)(sm + ((row * 384 + 2 * c) ^ ((row & 7) << 4))) =
                        (__bf16)gelu_fast(acc3[rt][ct][r]);
                }
    }
    __syncthreads();  // h2 (both halves) visible

    // ---- C4: out = h2 @ oW2 + b2, K=384 (h2 cols 0..191 in region B, 192..383 in region A)
    f32x4 acc4[4][3];
    #pragma unroll
    for (int ct = 0; ct < 3; ++ct) {
        float b2v = out_b2[wc + ct * 16 + lr];
        #pragma unroll
        for (int rt = 0; rt < 4; ++rt) acc4[rt][ct] = splat4(b2v);
    }
    #pragma unroll
    for (int ks = 0; ks < 12; ++ks) {
        const int base = (ks < 6) ? 24576 : 0;
        const int ksl = (ks < 6) ? ks : ks - 6;
        bf16x8 a[4], b[3];
        #pragma unroll
        for (int rt = 0; rt < 4; ++rt) {
            int row = rt * 16 + lr;
            a[rt] = *(const bf16x8*)(sm + base + ((row * 384 + ksl * 64 + lg * 16) ^ ((row & 7) << 4)));
        }
        #pragma unroll
        for (int ct = 0; ct < 3; ++ct) {
            int tt = w * 3 + ct;
            b[ct] = *(const bf16x8*)(oW2t + (tt * 16 + lr) * 384 + ks * 32 + lg * 8);
        }
        #pragma unroll
        for (int rt = 0; rt < 4; ++rt)
            #pragma unroll
            for (int ct = 0; ct < 3; ++ct)
                acc4[rt][ct] = __builtin_amdgcn_mfma_f32_16x16x32_bf16(a[rt], b[ct], acc4[rt][ct], 0, 0, 0);
    }

    // ---- store
    #pragma unroll
    for (int rt = 0; rt < 4; ++rt)
        #pragma unroll
        for (int ct = 0; ct < 3; ++ct)
            #pragma unroll
            for (int r = 0; r < 4; ++r)
                out[(mb + rt * 16 + lg * 4 + r) * 192 + wc + ct * 16 + lr] = acc4[rt][ct][r];
}

extern "C" void kernel_launch(void* const* d_in, const int* in_sizes, int n_in,
                              void* d_out, int out_size, void* d_ws, size_t ws_size,
                              hipStream_t stream) {
    const float* flags  = (const float*)d_in[0];
    const float* cons   = (const float*)d_in[1];
    const int* from_sq  = (const int*)d_in[2];
    const int* to_sq    = (const int*)d_in[3];
    const int* kind_id  = (const int*)d_in[4];
    const int* promo_id = (const int*)d_in[5];
    const int* meta_id  = (const int*)d_in[6];
    const int* mover    = (const int*)d_in[7];
    const int* target   = (const int*)d_in[8];
    const float* gctx   = (const float*)d_in[9];
    const float* piece  = (const float*)d_in[10];
    const float* sqe    = (const float*)d_in[11];
    const float* kinde  = (const float*)d_in[12];
    const float* promoe = (const float*)d_in[13];
    const float* metae  = (const float*)d_in[14];
    const float* fW1    = (const float*)d_in[15];
    const float* fb1    = (const float*)d_in[16];
    const float* fW2    = (const float*)d_in[17];
    const float* fb2    = (const float*)d_in[18];
    const float* cW1    = (const float*)d_in[19];
    const float* cb1    = (const float*)d_in[20];
    const float* cW2    = (const float*)d_in[21];
    const float* cb2    = (const float*)d_in[22];
    const float* lng    = (const float*)d_in[23];
    const float* lnb    = (const float*)d_in[24];
    const float* oW1    = (const float*)d_in[25];
    const float* ob1    = (const float*)d_in[26];
    const float* oW2    = (const float*)d_in[27];
    const float* ob2    = (const float*)d_in[28];
    float* out = (float*)d_out;
    int N = in_sizes[2];

    __bf16* ws = (__bf16*)d_ws;
    const __bf16* cW1t = ws;
    const __bf16* cW2t = ws + 12288;
    const __bf16* oW1t = ws + 86016;
    const __bf16* oW2t = ws + 159744;
    float* ftab = (float*)(ws + 233472);
    uint2* pkbuf = (uint2*)((char*)d_ws + 860160);

    prep_w<<<912, 256, 0, stream>>>(cW1, cW2, oW1, oW2, ws);
    prep_ft<<<128, 192, 0, stream>>>(fW1, fb1, fW2, fb2, ftab);
    prep_pack<<<(N + 255) / 256, 256, 0, stream>>>(flags, from_sq, to_sq, kind_id, promo_id,
                                                   meta_id, mover, target, pkbuf, N);
    me_main<<<N / 64, 256, 0, stream>>>(cons, pkbuf, gctx, piece, sqe, kinde, promoe, metae,
                                        cb1, cb2, lng, lnb, ob1, ob2,
                                        cW1t, cW2t, oW1t, oW2t, ftab, out);
}

// Round 7
// 760.021 us; speedup vs baseline: 1.2811x; 1.2811x over previous
//
#include <hip/hip_runtime.h>

#define DI __device__ __forceinline__

typedef __bf16 bf16x8 __attribute__((ext_vector_type(8)));
typedef __bf16 bf16x4 __attribute__((ext_vector_type(4)));
typedef float  f32x4  __attribute__((ext_vector_type(4)));
typedef float  f32x2  __attribute__((ext_vector_type(2)));

DI f32x4 splat4(float b) { f32x4 v; v[0] = b; v[1] = b; v[2] = b; v[3] = b; return v; }

// tanh-form GELU: gelu(x) = x / (1 + exp(-2u)), u = 0.79788456(x + 0.044715x^3)
DI float gelu_fast(float x) {
    float x3 = x * x * x;
    float z = -1.5957691216057308f * fmaf(0.044715f, x3, x);
    float e = __expf(z);
    return __fdividef(x, 1.0f + e);
}

// ---------------- ws layout (bytes) ----------------
// [0,      24576)   cW1t  bf16 [384][32]  (K padded 12->32)
// [24576,  172032)  cW2t  bf16 [192][384]
// [172032, 319488)  oW1t  bf16 [384][192]
// [319488, 466944)  oW2t  bf16 [192][384]
// [466944, 799488)  arena f32 [433][192]: piece@0(65) sqe@65(65) kinde@130(41)
//                                         promoe@171(5) metae@176(129) ftab@305(128)
// [802816, 4997120) pk4   uint4[N]: 8x u16 arena row ids
//                   {mover, target, 65+from, 65+to, 130+kind, 171+promo, 176+meta, 305+fc}
// x (f32 [N][192]) lives in d_out between K1 and K2.

__global__ void prep_w(const float* __restrict__ cW1, const float* __restrict__ cW2,
                       const float* __restrict__ oW1, const float* __restrict__ oW2,
                       __bf16* __restrict__ ws) {
    int id = blockIdx.x * 256 + threadIdx.x;
    if (id < 12288) {
        int n = id >> 5, k = id & 31;
        ws[id] = (k < 12) ? (__bf16)cW1[k * 384 + n] : (__bf16)0.0f;
    } else if (id < 86016) {
        int t = id - 12288;
        int n = t / 384, k = t % 384;
        ws[id] = (__bf16)cW2[k * 192 + n];
    } else if (id < 159744) {
        int t = id - 86016;
        int n = t / 192, k = t % 192;
        ws[id] = (__bf16)oW1[k * 384 + n];
    } else if (id < 233472) {
        int t = id - 159744;
        int n = t / 384, k = t % 384;
        ws[id] = (__bf16)oW2[k * 192 + n];
    }
}

__global__ void prep_arena(const float* __restrict__ piece, const float* __restrict__ sqe,
                           const float* __restrict__ kinde, const float* __restrict__ promoe,
                           const float* __restrict__ metae, float* __restrict__ arena) {
    int id = blockIdx.x * 256 + threadIdx.x;
    if (id >= 305 * 192) return;
    int row = id / 192, c = id % 192;
    float v;
    if (row < 65) v = piece[row * 192 + c];
    else if (row < 130) v = sqe[(row - 65) * 192 + c];
    else if (row < 171) v = kinde[(row - 130) * 192 + c];
    else if (row < 176) v = promoe[(row - 171) * 192 + c];
    else v = metae[(row - 176) * 192 + c];
    arena[id] = v;
}

// flag projection table -> arena rows 305..432 (exact erf GELU, f32)
__global__ void prep_ft(const float* __restrict__ W1, const float* __restrict__ b1,
                        const float* __restrict__ W2, const float* __restrict__ b2,
                        float* __restrict__ ftab) {
    __shared__ float h[384];
    int c = blockIdx.x;
    int tid = threadIdx.x;  // 0..191
    #pragma unroll
    for (int half = 0; half < 2; ++half) {
        int j = tid + half * 192;
        float v = b1[j];
        #pragma unroll
        for (int i = 0; i < 7; ++i)
            if (c & (1 << i)) v += W1[i * 384 + j];
        h[j] = 0.5f * v * (1.0f + erff(v * 0.70710678118654752f));
    }
    __syncthreads();
    float acc = b2[tid];
    for (int j = 0; j < 384; ++j)
        acc += h[j] * W2[j * 192 + tid];
    ftab[c * 192 + tid] = acc;
}

__global__ void prep_pack2(const float* __restrict__ flags,
                           const int* __restrict__ from_sq, const int* __restrict__ to_sq,
                           const int* __restrict__ kind_id, const int* __restrict__ promo_id,
                           const int* __restrict__ meta_id, const int* __restrict__ mover,
                           const int* __restrict__ target, uint4* __restrict__ pk4, int N) {
    int t = blockIdx.x * 256 + threadIdx.x;
    if (t >= N) return;
    unsigned fc = 0;
    #pragma unroll
    for (int i = 0; i < 7; ++i) fc |= (flags[t * 7 + i] > 0.5f) ? (1u << i) : 0u;
    uint4 v;
    v.x = (unsigned)mover[t] | (((unsigned)target[t]) << 16);
    v.y = (65u + (unsigned)from_sq[t]) | ((65u + (unsigned)to_sq[t]) << 16);
    v.z = (130u + (unsigned)kind_id[t]) | ((171u + (unsigned)promo_id[t]) << 16);
    v.w = (176u + (unsigned)meta_id[t]) | ((305u + fc) << 16);
    pk4[t] = v;
}

// ---------------- K1: C1 -> gather -> C2 -> LN -> x(f32) to d_out ----------------
// 4 waves x 64 moves; wave w owns cols [w*48, w*48+48).
// LDS: [0,49152) h1 bf16 [64][384] swizzled, later x f32 [64][192] swizzled
//      [49152,51200) LN partials [64][4][2] f32
__global__ __launch_bounds__(256, 2) void me_tok(
    const float* __restrict__ cons, const uint4* __restrict__ pk4,
    const float* __restrict__ arena,
    const float* __restrict__ gctx, const float* __restrict__ cons_b1,
    const float* __restrict__ cons_b2, const float* __restrict__ ln_g,
    const float* __restrict__ ln_b,
    const __bf16* __restrict__ cW1t, const __bf16* __restrict__ cW2t,
    float* __restrict__ xout) {
    __shared__ __align__(16) char sm[51200];
    float* P = (float*)(sm + 49152);
    const int tid = threadIdx.x;
    const int w = tid >> 6;
    const int lane = tid & 63;
    const int lg = lane >> 4;
    const int lr = lane & 15;
    const int mb = blockIdx.x * 64;
    const int wc = w * 48;

    // ---- C1 FIRST (no acc2 co-live): h1 = gelu(cons @ W1 + b1) -> LDS
    {
        bf16x8 af[4];
        #pragma unroll
        for (int rt = 0; rt < 4; ++rt) {
            int M = mb + rt * 16 + lr;
            #pragma unroll
            for (int i = 0; i < 8; ++i) {
                int k = lg * 8 + i;
                float v = (k < 12) ? cons[M * 12 + k] : 0.0f;
                af[rt][i] = (__bf16)v;
            }
        }
        #pragma unroll
        for (int hh = 0; hh < 2; ++hh) {
            #pragma unroll
            for (int rp = 0; rp < 2; ++rp) {
                f32x4 acc1[2][3];
                #pragma unroll
                for (int ct = 0; ct < 3; ++ct) {
                    int n0 = w * 96 + hh * 48 + ct * 16;
                    float b1v = cons_b1[n0 + lr];
                    bf16x8 bf = *(const bf16x8*)(cW1t + (n0 + lr) * 32 + lg * 8);
                    #pragma unroll
                    for (int rr = 0; rr < 2; ++rr)
                        acc1[rr][ct] = __builtin_amdgcn_mfma_f32_16x16x32_bf16(af[rp * 2 + rr], bf, splat4(b1v), 0, 0, 0);
                }
                #pragma unroll
                for (int rr = 0; rr < 2; ++rr)
                    #pragma unroll
                    for (int ct = 0; ct < 3; ++ct)
                        #pragma unroll
                        for (int r = 0; r < 4; ++r) {
                            int row = (rp * 2 + rr) * 16 + lg * 4 + r;
                            int col = w * 96 + hh * 48 + ct * 16 + lr;
                            *(__bf16*)(sm + ((row * 768 + 2 * col) ^ ((row & 7) << 4))) =
                                (__bf16)gelu_fast(acc1[rr][ct][r]);
                        }
            }
        }
    }
    __syncthreads();  // h1 complete

    // ---- gather: tok = sum of 8 arena rows + basev, in MFMA C-layout
    f32x4 acc2[4][3];
    {
        float basev[3];
        #pragma unroll
        for (int ct = 0; ct < 3; ++ct) {
            int n = wc + ct * 16 + lr;
            basev[ct] = gctx[n] + cons_b2[n];
        }
        const float* ab = arena + wc + lr;  // lane-fixed col base
        #pragma unroll
        for (int rt = 0; rt < 4; ++rt) {
            #pragma unroll
            for (int r = 0; r < 4; ++r) {
                int M = mb + rt * 16 + lg * 4 + r;
                uint4 q = pk4[M];
                #pragma unroll
                for (int ct = 0; ct < 3; ++ct) acc2[rt][ct][r] = basev[ct];
                #pragma unroll
                for (int t = 0; t < 8; ++t) {
                    unsigned word = (t < 2) ? q.x : (t < 4) ? q.y : (t < 6) ? q.z : q.w;
                    unsigned rowid = (t & 1) ? (word >> 16) : (word & 0xffffu);
                    const float* p = ab + rowid * 192;
                    #pragma unroll
                    for (int ct = 0; ct < 3; ++ct)
                        acc2[rt][ct][r] += p[ct * 16];
                }
            }
        }
    }

    // ---- C2: tok += h1 @ cons_W2 (K=384), rt-pairs to cap frag pressure
    #pragma unroll
    for (int rp = 0; rp < 2; ++rp) {
        #pragma unroll
        for (int ks = 0; ks < 12; ++ks) {
            bf16x8 a[2], b[3];
            #pragma unroll
            for (int rr = 0; rr < 2; ++rr) {
                int row = (rp * 2 + rr) * 16 + lr;
                a[rr] = *(const bf16x8*)(sm + ((row * 768 + ks * 64 + lg * 16) ^ ((row & 7) << 4)));
            }
            #pragma unroll
            for (int ct = 0; ct < 3; ++ct)
                b[ct] = *(const bf16x8*)(cW2t + (wc + ct * 16 + lr) * 384 + ks * 32 + lg * 8);
            #pragma unroll
            for (int rr = 0; rr < 2; ++rr)
                #pragma unroll
                for (int ct = 0; ct < 3; ++ct)
                    acc2[rp * 2 + rr][ct] = __builtin_amdgcn_mfma_f32_16x16x32_bf16(a[rr], b[ct], acc2[rp * 2 + rr][ct], 0, 0, 0);
        }
    }

    // ---- LN partials
    #pragma unroll
    for (int rt = 0; rt < 4; ++rt) {
        #pragma unroll
        for (int r = 0; r < 4; ++r) {
            float v0 = acc2[rt][0][r], v1 = acc2[rt][1][r], v2 = acc2[rt][2][r];
            float s = v0 + v1 + v2;
            float s2 = v0 * v0 + v1 * v1 + v2 * v2;
            s += __shfl_xor(s, 1); s2 += __shfl_xor(s2, 1);
            s += __shfl_xor(s, 2); s2 += __shfl_xor(s2, 2);
            s += __shfl_xor(s, 4); s2 += __shfl_xor(s2, 4);
            s += __shfl_xor(s, 8); s2 += __shfl_xor(s2, 8);
            if (lr == 0) {
                int row = rt * 16 + lg * 4 + r;
                f32x2 pv; pv[0] = s; pv[1] = s2;
                *(f32x2*)(P + row * 8 + w * 2) = pv;
            }
        }
    }
    __syncthreads();  // partials visible; h1 reads done -> LDS reusable

    // ---- LN finalize -> x f32 [64][192] swizzled into LDS [0,49152)
    {
        float lngv[3], lnbv[3];
        #pragma unroll
        for (int ct = 0; ct < 3; ++ct) {
            int n = wc + ct * 16 + lr;
            lngv[ct] = ln_g[n];
            lnbv[ct] = ln_b[n];
        }
        #pragma unroll
        for (int rt = 0; rt < 4; ++rt) {
            #pragma unroll
            for (int r = 0; r < 4; ++r) {
                int row = rt * 16 + lg * 4 + r;
                f32x4 pa = *(const f32x4*)(P + row * 8);
                f32x4 pb = *(const f32x4*)(P + row * 8 + 4);
                float s = pa[0] + pa[2] + pb[0] + pb[2];
                float s2 = pa[1] + pa[3] + pb[1] + pb[3];
                float mu = s * (1.0f / 192.0f);
                float var = s2 * (1.0f / 192.0f) - mu * mu;
                float inv = rsqrtf(var + 1e-5f);
                #pragma unroll
                for (int ct = 0; ct < 3; ++ct) {
                    int n = wc + ct * 16 + lr;
                    float xv = (acc2[rt][ct][r] - mu) * inv * lngv[ct] + lnbv[ct];
                    *(float*)(sm + row * 768 + ((n * 4) ^ ((row & 7) << 4))) = xv;
                }
            }
        }
    }
    __syncthreads();  // x complete in LDS

    // ---- coalesced copy LDS -> xout (d_out), unswizzling 16B blocks
    #pragma unroll
    for (int i = 0; i < 12; ++i) {
        int idx = tid + i * 256;           // 0..3071 = 64 rows x 48 float4
        int row = idx / 48, q = idx % 48;
        f32x4 v = *(const f32x4*)(sm + row * 768 + ((q * 16) ^ ((row & 7) << 4)));
        *(f32x4*)(xout + (mb + row) * 192 + q * 4) = v;
    }
}

// ---------------- K2: x -> h2=gelu(x@oW1+b1) -> out = h2@oW2 + b2 ----------------
// LDS: [0,24576) xb bf16 [64][192] swizzled; [24576,73728) h2 bf16 [64][384] swizzled
__global__ __launch_bounds__(256, 2) void me_out(
    const float* __restrict__ xin,  // d_out rows (read then overwritten by same block)
    const float* __restrict__ out_b1, const float* __restrict__ out_b2,
    const __bf16* __restrict__ oW1t, const __bf16* __restrict__ oW2t,
    float* __restrict__ out) {
    __shared__ __align__(16) char sm[73728];
    const int tid = threadIdx.x;
    const int w = tid >> 6;
    const int lane = tid & 63;
    const int lg = lane >> 4;
    const int lr = lane & 15;
    const int mb = blockIdx.x * 64;
    const int wc = w * 48;

    // ---- stage x (f32 global, fully coalesced) -> bf16 LDS swizzled
    #pragma unroll
    for (int i = 0; i < 12; ++i) {
        int idx = tid + i * 256;           // 64 rows x 48 float4
        int row = idx / 48, q = idx % 48;
        f32x4 v = *(const f32x4*)(xin + (mb + row) * 192 + q * 4);
        bf16x4 b; b[0] = (__bf16)v[0]; b[1] = (__bf16)v[1]; b[2] = (__bf16)v[2]; b[3] = (__bf16)v[3];
        *(bf16x4*)(sm + row * 384 + ((q * 8) ^ ((row & 7) << 4))) = b;
    }
    __syncthreads();

    // ---- C3: h2 cols [w*96, w*96+96) = gelu(x @ oW1 + b1), rt-pairs
    #pragma unroll
    for (int rp = 0; rp < 2; ++rp) {
        f32x4 acc3[2][6];
        #pragma unroll
        for (int cc = 0; cc < 6; ++cc) {
            float b1v = out_b1[w * 96 + cc * 16 + lr];
            #pragma unroll
            for (int rr = 0; rr < 2; ++rr) acc3[rr][cc] = splat4(b1v);
        }
        #pragma unroll
        for (int ks = 0; ks < 6; ++ks) {
            bf16x8 a[2], b[6];
            #pragma unroll
            for (int rr = 0; rr < 2; ++rr) {
                int row = (rp * 2 + rr) * 16 + lr;
                a[rr] = *(const bf16x8*)(sm + row * 384 + ((ks * 64 + lg * 16) ^ ((row & 7) << 4)));
            }
            #pragma unroll
            for (int cc = 0; cc < 6; ++cc)
                b[cc] = *(const bf16x8*)(oW1t + (w * 96 + cc * 16 + lr) * 192 + ks * 32 + lg * 8);
            #pragma unroll
            for (int rr = 0; rr < 2; ++rr)
                #pragma unroll
                for (int cc = 0; cc < 6; ++cc)
                    acc3[rr][cc] = __builtin_amdgcn_mfma_f32_16x16x32_bf16(a[rr], b[cc], acc3[rr][cc], 0, 0, 0);
        }
        #pragma unroll
        for (int rr = 0; rr < 2; ++rr)
            #pragma unroll
            for (int cc = 0; cc < 6; ++cc)
                #pragma unroll
                for (int r = 0; r < 4; ++r) {
                    int row = (rp * 2 + rr) * 16 + lg * 4 + r;
                    int col = w * 96 + cc * 16 + lr;
                    *(__bf16*)(sm + 24576 + row * 768 + ((2 * col) ^ ((row & 7) << 4))) =
                        (__bf16)gelu_fast(acc3[rr][cc][r]);
                }
    }
    __syncthreads();  // h2 complete

    // ---- C4: out = h2 @ oW2 + b2 (K=384)
    f32x4 acc4[4][3];
    #pragma unroll
    for (int ct = 0; ct < 3; ++ct) {
        float b2v = out_b2[wc + ct * 16 + lr];
        #pragma unroll
        for (int rt = 0; rt < 4; ++rt) acc4[rt][ct] = splat4(b2v);
    }
    #pragma unroll
    for (int ks = 0; ks < 12; ++ks) {
        bf16x8 a[4], b[3];
        #pragma unroll
        for (int rt = 0; rt < 4; ++rt) {
            int row = rt * 16 + lr;
            a[rt] = *(const bf16x8*)(sm + 24576 + row * 768 + ((ks * 64 + lg * 16) ^ ((row & 7) << 4)));
        }
        #pragma unroll
        for (int ct = 0; ct < 3; ++ct)
            b[ct] = *(const bf16x8*)(oW2t + (wc + ct * 16 + lr) * 384 + ks * 32 + lg * 8);
        #pragma unroll
        for (int rt = 0; rt < 4; ++rt)
            #pragma unroll
            for (int ct = 0; ct < 3; ++ct)
                acc4[rt][ct] = __builtin_amdgcn_mfma_f32_16x16x32_bf16(a[rt], b[ct], acc4[rt][ct], 0, 0, 0);
    }

    #pragma unroll
    for (int rt = 0; rt < 4; ++rt)
        #pragma unroll
        for (int ct = 0; ct < 3; ++ct)
            #pragma unroll
            for (int r = 0; r < 4; ++r)
                out[(mb + rt * 16 + lg * 4 + r) * 192 + wc + ct * 16 + lr] = acc4[rt][ct][r];
}

extern "C" void kernel_launch(void* const* d_in, const int* in_sizes, int n_in,
                              void* d_out, int out_size, void* d_ws, size_t ws_size,
                              hipStream_t stream) {
    const float* flags  = (const float*)d_in[0];
    const float* cons   = (const float*)d_in[1];
    const int* from_sq  = (const int*)d_in[2];
    const int* to_sq    = (const int*)d_in[3];
    const int* kind_id  = (const int*)d_in[4];
    const int* promo_id = (const int*)d_in[5];
    const int* meta_id  = (const int*)d_in[6];
    const int* mover    = (const int*)d_in[7];
    const int* target   = (const int*)d_in[8];
    const float* gctx   = (const float*)d_in[9];
    const float* piece  = (const float*)d_in[10];
    const float* sqe    = (const float*)d_in[11];
    const float* kinde  = (const float*)d_in[12];
    const float* promoe = (const float*)d_in[13];
    const float* metae  = (const float*)d_in[14];
    const float* fW1    = (const float*)d_in[15];
    const float* fb1    = (const float*)d_in[16];
    const float* fW2    = (const float*)d_in[17];
    const float* fb2    = (const float*)d_in[18];
    const float* cW1    = (const float*)d_in[19];
    const float* cb1    = (const float*)d_in[20];
    const float* cW2    = (const float*)d_in[21];
    const float* cb2    = (const float*)d_in[22];
    const float* lng    = (const float*)d_in[23];
    const float* lnb    = (const float*)d_in[24];
    const float* oW1    = (const float*)d_in[25];
    const float* ob1    = (const float*)d_in[26];
    const float* oW2    = (const float*)d_in[27];
    const float* ob2    = (const float*)d_in[28];
    float* out = (float*)d_out;
    int N = in_sizes[2];

    __bf16* ws = (__bf16*)d_ws;
    const __bf16* cW1t = ws;
    const __bf16* cW2t = ws + 12288;
    const __bf16* oW1t = ws + 86016;
    const __bf16* oW2t = ws + 159744;
    float* arena = (float*)((char*)d_ws + 466944);
    uint4* pk4 = (uint4*)((char*)d_ws + 802816);

    prep_w<<<912, 256, 0, stream>>>(cW1, cW2, oW1, oW2, ws);
    prep_arena<<<229, 256, 0, stream>>>(piece, sqe, kinde, promoe, metae, arena);
    prep_ft<<<128, 192, 0, stream>>>(fW1, fb1, fW2, fb2, arena + 305 * 192);
    prep_pack2<<<(N + 255) / 256, 256, 0, stream>>>(flags, from_sq, to_sq, kind_id, promo_id,
                                                    meta_id, mover, target, pk4, N);
    me_tok<<<N / 64, 256, 0, stream>>>(cons, pk4, arena, gctx, cb1, cb2, lng, lnb,
                                       cW1t, cW2t, out);
    me_out<<<N / 64, 256, 0, stream>>>(out, ob1, ob2, oW1t, oW2t, out);
}